// Round 16
// baseline (366.271 us; speedup 1.0000x reference)
//
#include <hip/hip_runtime.h>
#include <math.h>

#define NN 8192
#define EE 262144
#define GG 64
#define CC 10
#define KK1 4096
#define KK2 2048
#define KK3 1024
#define PITCH 128   // ELL row pitch; max in-degree of Poisson(32) is ~60, 128 is safe

typedef unsigned long long ull;

__device__ __forceinline__ float eluf(float x) { return x > 0.f ? x : expm1f(x); }
__device__ __forceinline__ float sigf(float x) { return 1.f / (1.f + expf(-x)); }
__device__ __forceinline__ unsigned f2s(float f) {
    unsigned u = __float_as_uint(f);
    return (u & 0x80000000u) ? ~u : (u | 0x80000000u);
}

// ---- fused init: blocks [0,1024) edge pass (ELL scatter + gstart);
//      blocks [1024,1280) gemm1 (x @ W1 -> xW), independent work ----
__global__ void k_init(const int* __restrict__ ei, int* __restrict__ cnt1,
                       int* __restrict__ csr1, const int* __restrict__ batch,
                       int* __restrict__ gstart, const float* __restrict__ X,
                       const float* __restrict__ W, float* __restrict__ Y) {
    __shared__ float Xs[32][33];
    __shared__ float Ws[32][36];
    int tid = threadIdx.x;
    if ((int)blockIdx.x >= 1024) {
        // ---- gemm1: M=NN, K=128, F=32 ----
        int txn = tid & 7, tym = tid >> 3;
        int m0 = ((int)blockIdx.x - 1024) * 32;
        float4 acc = make_float4(0.f, 0.f, 0.f, 0.f);
        for (int k0 = 0; k0 < 128; k0 += 32) {
            int r = tid >> 3, c4 = (tid & 7) << 2;
            *(float4*)&Xs[r][c4] = *(const float4*)&X[(size_t)(m0 + r) * 128 + k0 + c4];
            *(float4*)&Ws[r][c4] = *(const float4*)&W[(size_t)(k0 + r) * 32 + c4];
            __syncthreads();
#pragma unroll 8
            for (int kk = 0; kk < 32; kk++) {
                float4 wv = *(const float4*)&Ws[kk][txn * 4];
                float xv = Xs[tym][kk];
                acc.x += xv * wv.x; acc.y += xv * wv.y;
                acc.z += xv * wv.z; acc.w += xv * wv.w;
            }
            __syncthreads();
        }
        *(float4*)&Y[(size_t)(m0 + tym) * 32 + txn * 4] = acc;
        return;
    }
    int e = blockIdx.x * 256 + tid;
    int s = ei[e], d = ei[EE + e];
    int pos = atomicAdd(&cnt1[d], 1);
    csr1[(d << 7) + pos] = s;
    if (e < NN) {
        int g = batch[e];
        int prev = (e == 0) ? -1 : batch[e - 1];
        for (int gg = prev + 1; gg <= g; gg++) gstart[gg] = e;
        if (e == NN - 1)
            for (int gg = g + 1; gg <= GG; gg++) gstart[gg] = NN;
    }
}

// ---- fused pooled-features + GEMM + subset-filter ----
template<int KPOOL, int F, int FOUT, int L1>
__global__ void k_pool_gemm_sub(const float* __restrict__ x, const float* __restrict__ score,
                                const int* __restrict__ idx, float* __restrict__ xW,
                                const float* __restrict__ W,
                                const int* __restrict__ csrP, const int* __restrict__ roffP,
                                const int* __restrict__ degP,
                                const int* __restrict__ invmap,
                                int* __restrict__ csrO, int* __restrict__ roffO,
                                int* __restrict__ degO, float* __restrict__ dinvO) {
    constexpr int MT = KPOOL / 32, NT = FOUT / 32, NPOOL = MT * NT;
    int tid = threadIdx.x;
    if ((int)blockIdx.x < NPOOL) {
        __shared__ float Xs[32][F + 4];
        __shared__ float Ws[32][36];
        __shared__ float sfac[32];
        __shared__ int sIdx[32];
        int mt = (int)blockIdx.x % MT, nt = (int)blockIdx.x / MT;
        int m0 = mt * 32, n0 = nt * 32;
        if (tid < 32) {
            int j = idx[m0 + tid];
            sIdx[tid] = j;
            sfac[tid] = sigf(score[j]);
        }
        __syncthreads();
        for (int i4 = tid; i4 < 32 * (F / 4); i4 += 256) {
            int r = i4 / (F / 4), c = i4 % (F / 4);
            float4 v = *(const float4*)&x[(size_t)sIdx[r] * F + c * 4];
            float sf = sfac[r];
            v.x = eluf(v.x * sf); v.y = eluf(v.y * sf);
            v.z = eluf(v.z * sf); v.w = eluf(v.w * sf);
            *(float4*)&Xs[r][c * 4] = v;
        }
        __syncthreads();
        int txn = tid & 7, tym = tid >> 3;
        float4 acc = make_float4(0.f, 0.f, 0.f, 0.f);
        for (int k0 = 0; k0 < F; k0 += 32) {
            {
                int r = tid >> 3, c4 = (tid & 7) << 2;
                *(float4*)&Ws[r][c4] = *(const float4*)&W[(size_t)(k0 + r) * FOUT + n0 + c4];
            }
            __syncthreads();
#pragma unroll 8
            for (int kk = 0; kk < 32; kk++) {
                float4 wv = *(const float4*)&Ws[kk][txn * 4];
                float xv = Xs[tym][k0 + kk];
                acc.x += xv * wv.x; acc.y += xv * wv.y;
                acc.z += xv * wv.z; acc.w += xv * wv.w;
            }
            __syncthreads();
        }
        *(float4*)&xW[(size_t)(m0 + tym) * FOUT + n0 + txn * 4] = acc;
        return;
    }
    int wid = (((int)blockIdx.x - NPOOL) * 256 + tid) >> 6;
    int lane = tid & 63;
    if (wid >= KPOOL) return;
    int j = idx[wid];
    int cnt = 0;
    if (L1) {
        int j0 = j << 7;
        int len = degP[j];                     // <= PITCH = 128
        int e0 = (lane < len) ? csrP[j0 + lane] : -1;
        int e1 = (64 + lane < len) ? csrP[j0 + 64 + lane] : -1;
        bool dup0 = false, dup1 = false;
        for (int q = 0; q < len - 1; q++) {
            int vq = (q < 64) ? __shfl(e0, q, 64) : __shfl(e1, q - 64, 64);
            if (lane > q && e0 == vq) dup0 = true;
            if (64 + lane > q && e1 == vq) dup1 = true;
        }
        {   // chunk 0
            bool sel = (lane < len) && !dup0;
            int val = 0;
            if (sel) { int v = invmap[e0]; if (v > 0) val = v - 1; else sel = false; }
            ull m = __ballot(sel);
            if (sel) { int off = __popcll(m & ((1ull << lane) - 1ull)); csrO[j0 + cnt + off] = val; }
            cnt += __popcll(m);
        }
        {   // chunk 1
            bool sel = (64 + lane < len) && !dup1;
            int val = 0;
            if (sel) { int v = invmap[e1]; if (v > 0) val = v - 1; else sel = false; }
            ull m = __ballot(sel);
            if (sel) { int off = __popcll(m & ((1ull << lane) - 1ull)); csrO[j0 + cnt + off] = val; }
            cnt += __popcll(m);
        }
        if (lane == 0) {
            roffO[wid] = j0;
            degO[wid] = cnt;
            dinvO[wid] = 1.f / sqrtf((float)(cnt + 1));
        }
    } else {
        int j0 = roffP[j];
        int len = degP[j];
        for (int base = 0; base < len; base += 64) {
            bool sel = false;
            int val = 0;
            if (base + lane < len) {
                int e = csrP[j0 + base + lane];
                int v = invmap[e];
                if (v > 0) { sel = true; val = v - 1; }
            }
            ull m = __ballot(sel);
            if (sel) { int off = __popcll(m & ((1ull << lane) - 1ull)); csrO[j0 + cnt + off] = val; }
            cnt += __popcll(m);
        }
        if (lane == 0) {
            roffO[wid] = j0;
            degO[wid] = cnt;
            dinvO[wid] = 1.f / sqrtf((float)(cnt + 1));
        }
    }
}

// ---- GEMM with fused unpool+concat+elu on the X operand, BN=32 ----
// inv is rank+1 encoded (0 = not selected)
__global__ void k_gemm_up(const float* __restrict__ xl, const int* __restrict__ inv,
                          const float* __restrict__ xr, int Fl, int Fr,
                          const float* __restrict__ W, float* __restrict__ Y,
                          int M, int K, int F) {
    __shared__ float Xs[32][33];
    __shared__ float Ws[32][36];
    __shared__ int sIdx[32];
    int tid = threadIdx.x;
    int txn = tid & 7, tym = tid >> 3;
    int m0 = blockIdx.x * 32, n0 = blockIdx.y * 32;
    if (tid < 32) sIdx[tid] = inv[m0 + tid];
    float4 acc = make_float4(0.f, 0.f, 0.f, 0.f);
    __syncthreads();
    for (int k0 = 0; k0 < K; k0 += 32) {
        {
            int r = tid >> 3, c4 = (tid & 7) << 2;
            int kk = k0 + c4;
            float4 v;
            if (kk < Fl) {           // Fl,Fr multiples of 32 -> whole float4 on one side
                int rr = sIdx[r];
                v = (rr > 0) ? *(const float4*)&xl[(size_t)(rr - 1) * Fl + kk]
                             : make_float4(0.f, 0.f, 0.f, 0.f);
            } else {
                v = *(const float4*)&xr[(size_t)(m0 + r) * Fr + (kk - Fl)];
            }
            v.x = eluf(v.x); v.y = eluf(v.y); v.z = eluf(v.z); v.w = eluf(v.w);
            *(float4*)&Xs[r][c4] = v;
            *(float4*)&Ws[r][c4] = *(const float4*)&W[(size_t)(k0 + r) * F + n0 + c4];
        }
        __syncthreads();
#pragma unroll 8
        for (int kk = 0; kk < 32; kk++) {
            float4 wv = *(const float4*)&Ws[kk][txn * 4];
            float xv = Xs[tym][kk];
            acc.x += xv * wv.x; acc.y += xv * wv.y;
            acc.z += xv * wv.z; acc.w += xv * wv.w;
        }
        __syncthreads();
    }
    *(float4*)&Y[(size_t)(m0 + tym) * F + n0 + txn * 4] = acc;
}

// ---- split-row ELL/CSR gather propagate + self + bias + elu (+ score) ----
template<int LOGF, int SCORE, int L1, int LS>
__global__ void k_prop(const int* __restrict__ csr, const int* __restrict__ roff,
                       const int* __restrict__ deg, const float* __restrict__ dinv,
                       const float* __restrict__ xW, const float* __restrict__ b,
                       float* __restrict__ xout, const float* __restrict__ p,
                       float* __restrict__ score) {
    constexpr int FQ = 1 << (LOGF - 2);          // float4s per row
    constexpr int S = 1 << LS;                   // split factor
    constexpr int RL = FQ * S;                   // lanes per row
    const float4* xW4 = (const float4*)xW;
    int t = blockIdx.x * 256 + threadIdx.x;
    int d = t >> (LOGF - 2 + LS);
    int rem = t & (RL - 1);
    int q = rem >> LS, h = rem & (S - 1);
    int j0 = L1 ? (d << 7) : roff[d];
    int dg = deg[d];
    int j1 = j0 + dg;
    float dd = L1 ? (1.f / sqrtf((float)(dg + 1))) : dinv[d];
    int idx = (d << (LOGF - 2)) + q;
    float4 sum;
    if (h == 0) {
        float4 v0 = xW4[idx];
        sum = make_float4(dd * v0.x, dd * v0.y, dd * v0.z, dd * v0.w);
    } else {
        sum = make_float4(0.f, 0.f, 0.f, 0.f);
    }
    for (int j = j0 + h; j < j1; j += S) {
        int s = csr[j];
        float ds = L1 ? (1.f / sqrtf((float)(deg[s] + 1))) : dinv[s];
        float4 xv = xW4[(s << (LOGF - 2)) + q];
        sum.x += ds * xv.x; sum.y += ds * xv.y;
        sum.z += ds * xv.z; sum.w += ds * xv.w;
    }
#pragma unroll
    for (int m = 1; m < S; m <<= 1) {
        sum.x += __shfl_xor(sum.x, m, 64);
        sum.y += __shfl_xor(sum.y, m, 64);
        sum.z += __shfl_xor(sum.z, m, 64);
        sum.w += __shfl_xor(sum.w, m, 64);
    }
    float4 bv = *(const float4*)&b[q << 2];
    float4 o;
    o.x = eluf(dd * sum.x + bv.x);
    o.y = eluf(dd * sum.y + bv.y);
    o.z = eluf(dd * sum.z + bv.z);
    o.w = eluf(dd * sum.w + bv.w);
    if (h == 0) ((float4*)xout)[idx] = o;
    if (SCORE) {
        float4 pv = *(const float4*)&p[q << 2];
        float sc = 0.f, nr = 0.f;
        if (h == 0) {
            sc = o.x * pv.x + o.y * pv.y + o.z * pv.z + o.w * pv.w;
            nr = pv.x * pv.x + pv.y * pv.y + pv.z * pv.z + pv.w * pv.w;
        }
#pragma unroll
        for (int m = RL >> 1; m >= 1; m >>= 1) {
            sc += __shfl_xor(sc, m, 64);
            nr += __shfl_xor(nr, m, 64);
        }
        if (rem == 0) score[d] = sc / sqrtf(nr);
    }
}

// ---- gcn7 prop (LOGF=5, L1, S=8) + last-arrival fused readout ----
// Each block covers 4 contiguous rows; after writing + fence it adds its per-graph
// row counts; the block completing a graph's count runs that graph's finale.
__global__ void k_prop7(const int* __restrict__ csr, const int* __restrict__ deg,
                        const float* __restrict__ xW, const float* __restrict__ b,
                        float* __restrict__ x13, const int* __restrict__ batch,
                        const int* __restrict__ gstart, int* __restrict__ garr,
                        const float* __restrict__ Wl1, const float* __restrict__ Wc,
                        const float* __restrict__ bc, float* __restrict__ out) {
    const float4* xW4 = (const float4*)xW;
    int tid = threadIdx.x;
    int t = blockIdx.x * 256 + tid;
    int d = t >> 6;                  // RL = 64 (FQ=8, S=8)
    int rem = t & 63;
    int q = rem >> 3, h = rem & 7;
    int j0 = d << 7;
    int dg = deg[d];
    int j1 = j0 + dg;
    float dd = 1.f / sqrtf((float)(dg + 1));
    int idx = (d << 3) + q;
    float4 sum;
    if (h == 0) {
        float4 v0 = xW4[idx];
        sum = make_float4(dd * v0.x, dd * v0.y, dd * v0.z, dd * v0.w);
    } else {
        sum = make_float4(0.f, 0.f, 0.f, 0.f);
    }
    for (int j = j0 + h; j < j1; j += 8) {
        int s = csr[j];
        float ds = 1.f / sqrtf((float)(deg[s] + 1));
        float4 xv = xW4[(s << 3) + q];
        sum.x += ds * xv.x; sum.y += ds * xv.y;
        sum.z += ds * xv.z; sum.w += ds * xv.w;
    }
#pragma unroll
    for (int m = 1; m < 8; m <<= 1) {
        sum.x += __shfl_xor(sum.x, m, 64);
        sum.y += __shfl_xor(sum.y, m, 64);
        sum.z += __shfl_xor(sum.z, m, 64);
        sum.w += __shfl_xor(sum.w, m, 64);
    }
    float4 bv = *(const float4*)&b[q << 2];
    float4 o;
    o.x = eluf(dd * sum.x + bv.x);
    o.y = eluf(dd * sum.y + bv.y);
    o.z = eluf(dd * sum.z + bv.z);
    o.w = eluf(dd * sum.w + bv.w);
    if (h == 0) ((float4*)x13)[idx] = o;

    // ---- last-arrival per-graph completion ----
    __shared__ int doneG[4];
    __shared__ int nDone;
    __shared__ float sm[8][32], ss[8][32];
    __shared__ float h0s[64], h1s[64], lgs[CC];
    if (tid == 0) nDone = 0;
    __syncthreads();
    if (tid == 0) {
        __threadfence();             // release: make this block's x13 rows visible
        int r0 = blockIdx.x << 2;
        int g0 = batch[r0], g1 = batch[r0 + 3];
        int nd = 0;
        for (int g = g0; g <= g1; g++) {
            int lo = gstart[g] > r0 ? gstart[g] : r0;
            int hi = gstart[g + 1] < r0 + 4 ? gstart[g + 1] : r0 + 4;
            int c = hi - lo;
            int tot = gstart[g + 1] - gstart[g];
            if (c > 0 && atomicAdd(&garr[g], c) + c == tot) {
                __threadfence();     // acquire: order x13 reads after completion
                doneG[nd++] = g;
            }
        }
        nDone = nd;
    }
    __syncthreads();
    for (int ii = 0; ii < nDone; ii++) {
        int g = doneG[ii];
        int j0g = gstart[g], j1g = gstart[g + 1];
        int f = tid & 31, r = tid >> 5;
        float m = -INFINITY, s = 0.f;
        for (int j = j0g + r; j < j1g; j += 8) {
            float v = x13[(j << 5) + f];
            m = fmaxf(m, v);
            s += v;
        }
        sm[r][f] = m; ss[r][f] = s;
        __syncthreads();
        if (tid < 32) {
            float mm = sm[0][tid], sss = ss[0][tid];
            for (int i = 1; i < 8; i++) { mm = fmaxf(mm, sm[i][tid]); sss += ss[i][tid]; }
            h0s[tid] = eluf(mm);
            h0s[32 + tid] = eluf(sss / (float)(j1g - j0g));
        }
        __syncthreads();
        if (tid < 64) {
            float sumv = 0.f;
            for (int kk = 0; kk < 64; kk++) sumv += h0s[kk] * Wl1[kk * 64 + tid];
            h1s[tid] = eluf(sumv);
        }
        __syncthreads();
        if (tid < CC) {
            float sumv = bc[tid];
            for (int kk = 0; kk < 64; kk++) sumv += h1s[kk] * Wc[kk * CC + tid];
            lgs[tid] = sumv;
        }
        __syncthreads();
        if (tid == 0) {
            float mm = -1e30f;
            for (int c = 0; c < CC; c++) mm = fmaxf(mm, lgs[c]);
            float se = 0.f;
            for (int c = 0; c < CC; c++) se += expf(lgs[c] - mm);
            float lse = mm + logf(se);
            for (int c = 0; c < CC; c++) out[g * CC + c] = lgs[c] - lse;
        }
        __syncthreads();
    }
}

// ==== fused bitonic top-k: one kernel, internal device barriers ====
// Network identical to verified rounds; invmap written as rank+1 (0 = invalid).
// grid = N/2048 blocks of 1024 (<=4 blocks -> always co-resident, no deadlock).
__device__ __forceinline__ ull cex_shfl(ull v, int st, bool takeMax) {
    ull pv = __shfl_xor(v, st, 64);
    return takeMax ? (v > pv ? v : pv) : (v < pv ? v : pv);
}
__device__ __forceinline__ void cexr(ull& a, ull& b, bool desc) {
    if (desc ? (a < b) : (a > b)) { ull x = a; a = b; b = x; }
}

__global__ void k_topk_f(const float* __restrict__ score, ull* __restrict__ keys,
                         int N, int k, int* __restrict__ out_idx,
                         int* __restrict__ invmap, int* __restrict__ ctr) {
    __shared__ ull sk[4096];
    int tid = threadIdx.x;
    int bid = blockIdx.x;
    int nb = N >> 11;
    // ---- phase 1: full sort of 2048-key window [bid*2048, +2048) ----
    {
        int base = bid << 11;
        int giA = base + tid, giB = giA + 1024;
        ull a = ((ull)f2s(score[giA]) << 32) | (unsigned)(~giA);
        ull b = ((ull)f2s(score[giB]) << 32) | (unsigned)(~giB);
        for (int sz = 2; sz <= 2048; sz <<= 1) {
            int st = sz >> 1;
            if (st >= 64) {
                sk[tid] = a; sk[tid + 1024] = b;
                __syncthreads();
                for (; st >= 64; st >>= 1) {
                    int i = ((tid & ~(st - 1)) << 1) | (tid & (st - 1));
                    int j = i | st;
                    ull u = sk[i], v = sk[j];
                    bool desc = (((base + i) & sz) == 0);
                    if (desc ? (u < v) : (u > v)) { sk[i] = v; sk[j] = u; }
                    __syncthreads();
                }
                a = sk[tid]; b = sk[tid + 1024];
            }
            for (; st >= 1; st >>= 1) {
                bool low = (tid & st) == 0;
                a = cex_shfl(a, st, ((giA & sz) == 0) == low);
                b = cex_shfl(b, st, ((giB & sz) == 0) == low);
            }
        }
        if (nb == 1) {               // N == 2048: done
            if (giA < k) { int j = (int)(~(unsigned)(a & 0xFFFFFFFFu)); out_idx[giA] = j; invmap[j] = giA + 1; }
            if (giB < k) { int j = (int)(~(unsigned)(b & 0xFFFFFFFFu)); out_idx[giB] = j; invmap[j] = giB + 1; }
            return;
        }
        keys[giA] = a; keys[giB] = b;
    }
    // arrive (release: agent-scope fence writes back local L2)
    __syncthreads();
    if (tid == 0) { __threadfence(); atomicAdd(ctr, 1); }

    if (N == 4096) {
        if (bid != 0) return;
        if (tid == 0) { while (atomicAdd(ctr, 0) < 2) ; __threadfence(); }
        __syncthreads();
        // ---- stage sz=4096 final: ranks [0,2048) = k ----
        ull a0 = keys[tid],        a1 = keys[tid + 1024];
        ull a2 = keys[tid + 2048], a3 = keys[tid + 3072];
        cexr(a0, a2, true); cexr(a1, a3, true);      // stride 2048 (keep low half)
        sk[tid] = a0; sk[tid + 1024] = a1;
        __syncthreads();
        for (int st = 1024; st >= 64; st >>= 1) {
            int i = ((tid & ~(st - 1)) << 1) | (tid & (st - 1));
            int j = i | st;
            ull u = sk[i], v = sk[j];
            if (u < v) { sk[i] = v; sk[j] = u; }     // desc
            __syncthreads();
        }
        a0 = sk[tid]; a1 = sk[tid + 1024];
        for (int st = 32; st >= 1; st >>= 1) {
            bool low = (tid & st) == 0;
            a0 = cex_shfl(a0, st, low);
            a1 = cex_shfl(a1, st, low);
        }
        int p, j;
        p = tid;        j = (int)(~(unsigned)(a0 & 0xFFFFFFFFu)); out_idx[p] = j; invmap[j] = p + 1;
        p = tid + 1024; j = (int)(~(unsigned)(a1 & 0xFFFFFFFFu)); out_idx[p] = j; invmap[j] = p + 1;
        return;
    }

    // ---- N == 8192 ----
    if (bid >= 2) return;
    if (tid == 0) { while (atomicAdd(ctr, 0) < 4) ; __threadfence(); }
    __syncthreads();
    {
        // phase 2: stage sz=4096 complete on [bid*4096, +4096)
        int base = bid << 12;
        bool desc = ((base & 4096) == 0);
        ull k0 = keys[base + tid], k1 = keys[base + tid + 1024];
        ull k2 = keys[base + tid + 2048], k3 = keys[base + tid + 3072];
        cexr(k0, k2, desc); cexr(k1, k3, desc);      // stride 2048
        sk[tid] = k0; sk[tid + 1024] = k1; sk[tid + 2048] = k2; sk[tid + 3072] = k3;
        __syncthreads();
        for (int st = 1024; st >= 64; st >>= 1) {
            for (int pp = tid; pp < 2048; pp += 1024) {
                int i = ((pp & ~(st - 1)) << 1) | (pp & (st - 1));
                int j = i | st;
                ull u = sk[i], v = sk[j];
                if (desc ? (u < v) : (u > v)) { sk[i] = v; sk[j] = u; }
            }
            __syncthreads();
        }
        k0 = sk[tid]; k1 = sk[tid + 1024]; k2 = sk[tid + 2048]; k3 = sk[tid + 3072];
        for (int st = 32; st >= 1; st >>= 1) {
            bool low = (tid & st) == 0;
            k0 = cex_shfl(k0, st, desc == low);
            k1 = cex_shfl(k1, st, desc == low);
            k2 = cex_shfl(k2, st, desc == low);
            k3 = cex_shfl(k3, st, desc == low);
        }
        keys[base + tid] = k0; keys[base + tid + 1024] = k1;
        keys[base + tid + 2048] = k2; keys[base + tid + 3072] = k3;
    }
    __syncthreads();
    if (tid == 0) { __threadfence(); atomicAdd(ctr, 1); }
    if (bid != 0) return;
    if (tid == 0) { while (atomicAdd(ctr, 0) < 6) ; __threadfence(); }
    __syncthreads();
    {
        // phase 3: stage sz=8192 (desc everywhere); ranks [0,4096) = k
        ull a0 = keys[tid],        a1 = keys[tid + 1024];
        ull a2 = keys[tid + 2048], a3 = keys[tid + 3072];
        ull b0 = keys[tid + 4096], b1 = keys[tid + 5120];
        ull b2 = keys[tid + 6144], b3 = keys[tid + 7168];
        cexr(a0, b0, true); cexr(a1, b1, true);      // stride 4096 (keep low half)
        cexr(a2, b2, true); cexr(a3, b3, true);
        cexr(a0, a2, true); cexr(a1, a3, true);      // stride 2048 within [0,4096)
        sk[tid] = a0; sk[tid + 1024] = a1; sk[tid + 2048] = a2; sk[tid + 3072] = a3;
        __syncthreads();
        for (int st = 1024; st >= 64; st >>= 1) {
            for (int pp = tid; pp < 2048; pp += 1024) {
                int i = ((pp & ~(st - 1)) << 1) | (pp & (st - 1));
                int j = i | st;
                ull u = sk[i], v = sk[j];
                if (u < v) { sk[i] = v; sk[j] = u; } // desc
            }
            __syncthreads();
        }
        a0 = sk[tid]; a1 = sk[tid + 1024]; a2 = sk[tid + 2048]; a3 = sk[tid + 3072];
        for (int st = 32; st >= 1; st >>= 1) {
            bool low = (tid & st) == 0;
            a0 = cex_shfl(a0, st, low);
            a1 = cex_shfl(a1, st, low);
            a2 = cex_shfl(a2, st, low);
            a3 = cex_shfl(a3, st, low);
        }
        int p, j;
        p = tid;        j = (int)(~(unsigned)(a0 & 0xFFFFFFFFu)); out_idx[p] = j; invmap[j] = p + 1;
        p = tid + 1024; j = (int)(~(unsigned)(a1 & 0xFFFFFFFFu)); out_idx[p] = j; invmap[j] = p + 1;
        p = tid + 2048; j = (int)(~(unsigned)(a2 & 0xFFFFFFFFu)); out_idx[p] = j; invmap[j] = p + 1;
        p = tid + 3072; j = (int)(~(unsigned)(a3 & 0xFFFFFFFFu)); out_idx[p] = j; invmap[j] = p + 1;
    }
}

extern "C" void kernel_launch(void* const* d_in, const int* in_sizes, int n_in,
                              void* d_out, int out_size, void* d_ws, size_t ws_size,
                              hipStream_t stream) {
    const float* x = (const float*)d_in[0];
    const int* ei = (const int*)d_in[1];
    const int* batch = (const int*)d_in[2];
    const float* W1 = (const float*)d_in[3];  const float* b1 = (const float*)d_in[4];
    const float* W2 = (const float*)d_in[5];  const float* b2 = (const float*)d_in[6];
    const float* W3 = (const float*)d_in[7];  const float* b3 = (const float*)d_in[8];
    const float* W4 = (const float*)d_in[9];  const float* b4 = (const float*)d_in[10];
    const float* W5 = (const float*)d_in[11]; const float* b5 = (const float*)d_in[12];
    const float* W6 = (const float*)d_in[13]; const float* b6 = (const float*)d_in[14];
    const float* W7 = (const float*)d_in[15]; const float* b7 = (const float*)d_in[16];
    const float* p1 = (const float*)d_in[17];
    const float* p2 = (const float*)d_in[18];
    const float* p3 = (const float*)d_in[19];
    const float* Wl1 = (const float*)d_in[20];
    const float* Wc = (const float*)d_in[21];
    const float* bc = (const float*)d_in[22];
    float* out = (float*)d_out;
    (void)in_sizes; (void)n_in; (void)out_size; (void)ws_size;

    char* w = (char*)d_ws;
    size_t off = 0;
    auto alloc = [&](size_t bytes) -> char* {
        char* p = w + off;
        off = (off + bytes + 255) & ~(size_t)255;
        return p;
    };

    // ---- zero-initialized span (single small memset) ----
    size_t zero_begin = off;
    int* cnt1 = (int*)alloc(NN * 4);
    int* pos2 = (int*)alloc(NN * 4);     // orig -> level2 rank+1 (0 = invalid)
    int* inv4 = (int*)alloc(KK1 * 4);    // level2 -> level3 rank+1
    int* inv6 = (int*)alloc(KK2 * 4);    // level3 -> level4 rank+1
    int* tkctr = (int*)alloc(2 * 4);     // topk barrier counters (pool1, pool2)
    int* garr = (int*)alloc(GG * 4);     // per-graph arrival counters
    size_t zero_len = off - zero_begin;

    // ---- uninitialized scratch ----
    float* dinv2 = (float*)alloc(KK1 * 4);
    float* dinv3 = (float*)alloc(KK2 * 4);
    float* dinv4 = (float*)alloc(KK3 * 4);
    int* roff2 = (int*)alloc(KK1 * 4); int* deg2 = (int*)alloc(KK1 * 4);
    int* roff3 = (int*)alloc(KK2 * 4); int* deg3 = (int*)alloc(KK2 * 4);
    int* roff4 = (int*)alloc(KK3 * 4); int* deg4 = (int*)alloc(KK3 * 4);
    int* csr1 = (int*)alloc((size_t)NN * PITCH * 4);   // 4 MB ELL each
    int* csr2 = (int*)alloc((size_t)NN * PITCH * 4);
    int* csr3 = (int*)alloc((size_t)NN * PITCH * 4);
    int* csr4 = (int*)alloc((size_t)NN * PITCH * 4);
    float* xW = (float*)alloc((size_t)262144 * 4);
    float* x1 = (float*)alloc((size_t)NN * 32 * 4);
    float* x3 = (float*)alloc((size_t)KK1 * 64 * 4);
    float* x5 = (float*)alloc((size_t)KK2 * 128 * 4);
    float* x7 = (float*)alloc((size_t)KK3 * 256 * 4);
    float* x9 = (float*)alloc((size_t)KK2 * 128 * 4);
    float* x11 = (float*)alloc((size_t)KK1 * 64 * 4);
    float* x13 = (float*)alloc((size_t)NN * 32 * 4);
    float* score1 = (float*)alloc(NN * 4);
    float* score2 = (float*)alloc(KK1 * 4);
    float* score3 = (float*)alloc(KK2 * 4);
    int* i2 = (int*)alloc(KK1 * 4);
    int* i4 = (int*)alloc(KK2 * 4);
    int* i6 = (int*)alloc(KK3 * 4);
    ull* keys = (ull*)alloc((size_t)NN * 8);
    int* gstart = (int*)alloc((GG + 1) * 4);

    hipMemsetAsync(w + zero_begin, 0, zero_len, stream);

    const int B = 256;
    // ---- fused: level-1 edge pass (ELL scatter + gbounds) || gemm1 ----
    k_init<<<1280, B, 0, stream>>>(ei, cnt1, csr1, batch, gstart, x, W1, xW);

    // ---- gcn1 propagate (+score1), split S=8 ----
    k_prop<5, 1, 1, 3><<<2048, B, 0, stream>>>(csr1, nullptr, cnt1, nullptr, xW, b1,
                                               x1, p1, score1);

    // ---- pool1: top-4096 of 8192 (single fused kernel); pool+gemm2+subset ----
    k_topk_f<<<4, 1024, 0, stream>>>(score1, keys, NN, KK1, i2, pos2, tkctr);
    k_pool_gemm_sub<KK1, 32, 64, 1><<<256 + KK1 / 4, B, 0, stream>>>(
        x1, score1, i2, xW, W2, csr1, nullptr, cnt1, pos2, csr2, roff2, deg2, dinv2);

    // ---- gcn2 propagate (+score2), split S=4 ----
    k_prop<6, 1, 0, 2><<<1024, B, 0, stream>>>(csr2, roff2, deg2, dinv2, xW, b2,
                                               x3, p2, score2);

    // ---- pool2: top-2048 of 4096; pool+gemm3+subset ----
    k_topk_f<<<2, 1024, 0, stream>>>(score2, keys, KK1, KK2, i4, inv4, tkctr + 1);
    k_pool_gemm_sub<KK2, 64, 128, 0><<<256 + KK2 / 4, B, 0, stream>>>(
        x3, score2, i4, xW, W3, csr2, roff2, deg2, inv4, csr3, roff3, deg3, dinv3);

    // ---- gcn3 propagate (+score3), split S=2 ----
    k_prop<7, 1, 0, 1><<<512, B, 0, stream>>>(csr3, roff3, deg3, dinv3, xW, b3,
                                              x5, p3, score3);

    // ---- pool3: top-1024 of 2048; pool+gemm4+subset ----
    k_topk_f<<<1, 1024, 0, stream>>>(score3, keys, KK2, KK3, i6, inv6, nullptr);
    k_pool_gemm_sub<KK3, 128, 256, 0><<<256 + KK3 / 4, B, 0, stream>>>(
        x5, score3, i6, xW, W4, csr3, roff3, deg3, inv6, csr4, roff4, deg4, dinv4);

    // ---- gcn4 propagate, split S=2 ----
    k_prop<8, 0, 0, 1><<<512, B, 0, stream>>>(csr4, roff4, deg4, dinv4, xW, b4,
                                              x7, nullptr, nullptr);

    // ---- gcn5 (unpool3 fused into X staging), split S=4 ----
    k_gemm_up<<<dim3(KK2 / 32, 4), B, 0, stream>>>(x7, inv6, x5, 256, 128,
                                                   W5, xW, KK2, 384, 128);
    k_prop<7, 0, 0, 2><<<1024, B, 0, stream>>>(csr3, roff3, deg3, dinv3, xW, b5,
                                               x9, nullptr, nullptr);

    // ---- gcn6 (unpool2 fused), split S=4 ----
    k_gemm_up<<<dim3(KK1 / 32, 2), B, 0, stream>>>(x9, inv4, x3, 128, 64,
                                                   W6, xW, KK1, 192, 64);
    k_prop<6, 0, 0, 2><<<1024, B, 0, stream>>>(csr2, roff2, deg2, dinv2, xW, b6,
                                               x11, nullptr, nullptr);

    // ---- gcn7 (unpool1 fused) + fused last-arrival readout ----
    k_gemm_up<<<dim3(NN / 32, 1), B, 0, stream>>>(x11, pos2, x1, 64, 32,
                                                  W7, xW, NN, 96, 32);
    k_prop7<<<2048, B, 0, stream>>>(csr1, cnt1, xW, b7, x13, batch, gstart, garr,
                                    Wl1, Wc, bc, out);
}

// Round 17
// 309.041 us; speedup vs baseline: 1.1852x; 1.1852x over previous
//
#include <hip/hip_runtime.h>
#include <math.h>

#define NN 8192
#define EE 262144
#define GG 64
#define CC 10
#define KK1 4096
#define KK2 2048
#define KK3 1024
#define PITCH 128   // ELL row pitch; max in-degree of Poisson(32) is ~60, 128 is safe

typedef unsigned long long ull;

__device__ __forceinline__ float eluf(float x) { return x > 0.f ? x : expm1f(x); }
__device__ __forceinline__ float sigf(float x) { return 1.f / (1.f + expf(-x)); }
__device__ __forceinline__ unsigned f2s(float f) {
    unsigned u = __float_as_uint(f);
    return (u & 0x80000000u) ? ~u : (u | 0x80000000u);
}

// ---- fused init: blocks [0,1024) edge pass (ELL scatter + gstart);
//      blocks [1024,1280) gemm1 (x @ W1 -> xW), independent work ----
__global__ void k_init(const int* __restrict__ ei, int* __restrict__ cnt1,
                       int* __restrict__ csr1, const int* __restrict__ batch,
                       int* __restrict__ gstart, const float* __restrict__ X,
                       const float* __restrict__ W, float* __restrict__ Y) {
    __shared__ float Xs[32][33];
    __shared__ float Ws[32][36];
    int tid = threadIdx.x;
    if ((int)blockIdx.x >= 1024) {
        // ---- gemm1: M=NN, K=128, F=32 ----
        int txn = tid & 7, tym = tid >> 3;
        int m0 = ((int)blockIdx.x - 1024) * 32;
        float4 acc = make_float4(0.f, 0.f, 0.f, 0.f);
        for (int k0 = 0; k0 < 128; k0 += 32) {
            int r = tid >> 3, c4 = (tid & 7) << 2;
            *(float4*)&Xs[r][c4] = *(const float4*)&X[(size_t)(m0 + r) * 128 + k0 + c4];
            *(float4*)&Ws[r][c4] = *(const float4*)&W[(size_t)(k0 + r) * 32 + c4];
            __syncthreads();
#pragma unroll 8
            for (int kk = 0; kk < 32; kk++) {
                float4 wv = *(const float4*)&Ws[kk][txn * 4];
                float xv = Xs[tym][kk];
                acc.x += xv * wv.x; acc.y += xv * wv.y;
                acc.z += xv * wv.z; acc.w += xv * wv.w;
            }
            __syncthreads();
        }
        *(float4*)&Y[(size_t)(m0 + tym) * 32 + txn * 4] = acc;
        return;
    }
    int e = blockIdx.x * 256 + tid;
    int s = ei[e], d = ei[EE + e];
    int pos = atomicAdd(&cnt1[d], 1);
    csr1[(d << 7) + pos] = s;
    if (e < NN) {
        int g = batch[e];
        int prev = (e == 0) ? -1 : batch[e - 1];
        for (int gg = prev + 1; gg <= g; gg++) gstart[gg] = e;
        if (e == NN - 1)
            for (int gg = g + 1; gg <= GG; gg++) gstart[gg] = NN;
    }
}

// ---- fused pooled-features + GEMM + subset-filter ----
template<int KPOOL, int F, int FOUT, int L1>
__global__ void k_pool_gemm_sub(const float* __restrict__ x, const float* __restrict__ score,
                                const int* __restrict__ idx, float* __restrict__ xW,
                                const float* __restrict__ W,
                                const int* __restrict__ csrP, const int* __restrict__ roffP,
                                const int* __restrict__ degP,
                                const int* __restrict__ invmap,
                                int* __restrict__ csrO, int* __restrict__ roffO,
                                int* __restrict__ degO, float* __restrict__ dinvO) {
    constexpr int MT = KPOOL / 32, NT = FOUT / 32, NPOOL = MT * NT;
    int tid = threadIdx.x;
    if ((int)blockIdx.x < NPOOL) {
        __shared__ float Xs[32][F + 4];
        __shared__ float Ws[32][36];
        __shared__ float sfac[32];
        __shared__ int sIdx[32];
        int mt = (int)blockIdx.x % MT, nt = (int)blockIdx.x / MT;
        int m0 = mt * 32, n0 = nt * 32;
        if (tid < 32) {
            int j = idx[m0 + tid];
            sIdx[tid] = j;
            sfac[tid] = sigf(score[j]);
        }
        __syncthreads();
        for (int i4 = tid; i4 < 32 * (F / 4); i4 += 256) {
            int r = i4 / (F / 4), c = i4 % (F / 4);
            float4 v = *(const float4*)&x[(size_t)sIdx[r] * F + c * 4];
            float sf = sfac[r];
            v.x = eluf(v.x * sf); v.y = eluf(v.y * sf);
            v.z = eluf(v.z * sf); v.w = eluf(v.w * sf);
            *(float4*)&Xs[r][c * 4] = v;
        }
        __syncthreads();
        int txn = tid & 7, tym = tid >> 3;
        float4 acc = make_float4(0.f, 0.f, 0.f, 0.f);
        for (int k0 = 0; k0 < F; k0 += 32) {
            {
                int r = tid >> 3, c4 = (tid & 7) << 2;
                *(float4*)&Ws[r][c4] = *(const float4*)&W[(size_t)(k0 + r) * FOUT + n0 + c4];
            }
            __syncthreads();
#pragma unroll 8
            for (int kk = 0; kk < 32; kk++) {
                float4 wv = *(const float4*)&Ws[kk][txn * 4];
                float xv = Xs[tym][k0 + kk];
                acc.x += xv * wv.x; acc.y += xv * wv.y;
                acc.z += xv * wv.z; acc.w += xv * wv.w;
            }
            __syncthreads();
        }
        *(float4*)&xW[(size_t)(m0 + tym) * FOUT + n0 + txn * 4] = acc;
        return;
    }
    int wid = (((int)blockIdx.x - NPOOL) * 256 + tid) >> 6;
    int lane = tid & 63;
    if (wid >= KPOOL) return;
    int j = idx[wid];
    int cnt = 0;
    if (L1) {
        int j0 = j << 7;
        int len = degP[j];                     // <= PITCH = 128
        int e0 = (lane < len) ? csrP[j0 + lane] : -1;
        int e1 = (64 + lane < len) ? csrP[j0 + 64 + lane] : -1;
        bool dup0 = false, dup1 = false;
        for (int q = 0; q < len - 1; q++) {
            int vq = (q < 64) ? __shfl(e0, q, 64) : __shfl(e1, q - 64, 64);
            if (lane > q && e0 == vq) dup0 = true;
            if (64 + lane > q && e1 == vq) dup1 = true;
        }
        {   // chunk 0
            bool sel = (lane < len) && !dup0;
            int val = 0;
            if (sel) { int v = invmap[e0]; if (v > 0) val = v - 1; else sel = false; }
            ull m = __ballot(sel);
            if (sel) { int off = __popcll(m & ((1ull << lane) - 1ull)); csrO[j0 + cnt + off] = val; }
            cnt += __popcll(m);
        }
        {   // chunk 1
            bool sel = (64 + lane < len) && !dup1;
            int val = 0;
            if (sel) { int v = invmap[e1]; if (v > 0) val = v - 1; else sel = false; }
            ull m = __ballot(sel);
            if (sel) { int off = __popcll(m & ((1ull << lane) - 1ull)); csrO[j0 + cnt + off] = val; }
            cnt += __popcll(m);
        }
        if (lane == 0) {
            roffO[wid] = j0;
            degO[wid] = cnt;
            dinvO[wid] = 1.f / sqrtf((float)(cnt + 1));
        }
    } else {
        int j0 = roffP[j];
        int len = degP[j];
        for (int base = 0; base < len; base += 64) {
            bool sel = false;
            int val = 0;
            if (base + lane < len) {
                int e = csrP[j0 + base + lane];
                int v = invmap[e];
                if (v > 0) { sel = true; val = v - 1; }
            }
            ull m = __ballot(sel);
            if (sel) { int off = __popcll(m & ((1ull << lane) - 1ull)); csrO[j0 + cnt + off] = val; }
            cnt += __popcll(m);
        }
        if (lane == 0) {
            roffO[wid] = j0;
            degO[wid] = cnt;
            dinvO[wid] = 1.f / sqrtf((float)(cnt + 1));
        }
    }
}

// ---- GEMM with fused unpool+concat+elu on the X operand, BN=32 ----
// inv is rank+1 encoded (0 = not selected)
__global__ void k_gemm_up(const float* __restrict__ xl, const int* __restrict__ inv,
                          const float* __restrict__ xr, int Fl, int Fr,
                          const float* __restrict__ W, float* __restrict__ Y,
                          int M, int K, int F) {
    __shared__ float Xs[32][33];
    __shared__ float Ws[32][36];
    __shared__ int sIdx[32];
    int tid = threadIdx.x;
    int txn = tid & 7, tym = tid >> 3;
    int m0 = blockIdx.x * 32, n0 = blockIdx.y * 32;
    if (tid < 32) sIdx[tid] = inv[m0 + tid];
    float4 acc = make_float4(0.f, 0.f, 0.f, 0.f);
    __syncthreads();
    for (int k0 = 0; k0 < K; k0 += 32) {
        {
            int r = tid >> 3, c4 = (tid & 7) << 2;
            int kk = k0 + c4;
            float4 v;
            if (kk < Fl) {           // Fl,Fr multiples of 32 -> whole float4 on one side
                int rr = sIdx[r];
                v = (rr > 0) ? *(const float4*)&xl[(size_t)(rr - 1) * Fl + kk]
                             : make_float4(0.f, 0.f, 0.f, 0.f);
            } else {
                v = *(const float4*)&xr[(size_t)(m0 + r) * Fr + (kk - Fl)];
            }
            v.x = eluf(v.x); v.y = eluf(v.y); v.z = eluf(v.z); v.w = eluf(v.w);
            *(float4*)&Xs[r][c4] = v;
            *(float4*)&Ws[r][c4] = *(const float4*)&W[(size_t)(k0 + r) * F + n0 + c4];
        }
        __syncthreads();
#pragma unroll 8
        for (int kk = 0; kk < 32; kk++) {
            float4 wv = *(const float4*)&Ws[kk][txn * 4];
            float xv = Xs[tym][kk];
            acc.x += xv * wv.x; acc.y += xv * wv.y;
            acc.z += xv * wv.z; acc.w += xv * wv.w;
        }
        __syncthreads();
    }
    *(float4*)&Y[(size_t)(m0 + tym) * F + n0 + txn * 4] = acc;
}

// ---- split-row ELL/CSR gather propagate + self + bias + elu (+ score) ----
template<int LOGF, int SCORE, int L1, int LS>
__global__ void k_prop(const int* __restrict__ csr, const int* __restrict__ roff,
                       const int* __restrict__ deg, const float* __restrict__ dinv,
                       const float* __restrict__ xW, const float* __restrict__ b,
                       float* __restrict__ xout, const float* __restrict__ p,
                       float* __restrict__ score) {
    constexpr int FQ = 1 << (LOGF - 2);          // float4s per row
    constexpr int S = 1 << LS;                   // split factor
    constexpr int RL = FQ * S;                   // lanes per row
    const float4* xW4 = (const float4*)xW;
    int t = blockIdx.x * 256 + threadIdx.x;
    int d = t >> (LOGF - 2 + LS);
    int rem = t & (RL - 1);
    int q = rem >> LS, h = rem & (S - 1);
    int j0 = L1 ? (d << 7) : roff[d];
    int dg = deg[d];
    int j1 = j0 + dg;
    float dd = L1 ? (1.f / sqrtf((float)(dg + 1))) : dinv[d];
    int idx = (d << (LOGF - 2)) + q;
    float4 sum;
    if (h == 0) {
        float4 v0 = xW4[idx];
        sum = make_float4(dd * v0.x, dd * v0.y, dd * v0.z, dd * v0.w);
    } else {
        sum = make_float4(0.f, 0.f, 0.f, 0.f);
    }
    for (int j = j0 + h; j < j1; j += S) {
        int s = csr[j];
        float ds = L1 ? (1.f / sqrtf((float)(deg[s] + 1))) : dinv[s];
        float4 xv = xW4[(s << (LOGF - 2)) + q];
        sum.x += ds * xv.x; sum.y += ds * xv.y;
        sum.z += ds * xv.z; sum.w += ds * xv.w;
    }
#pragma unroll
    for (int m = 1; m < S; m <<= 1) {
        sum.x += __shfl_xor(sum.x, m, 64);
        sum.y += __shfl_xor(sum.y, m, 64);
        sum.z += __shfl_xor(sum.z, m, 64);
        sum.w += __shfl_xor(sum.w, m, 64);
    }
    float4 bv = *(const float4*)&b[q << 2];
    float4 o;
    o.x = eluf(dd * sum.x + bv.x);
    o.y = eluf(dd * sum.y + bv.y);
    o.z = eluf(dd * sum.z + bv.z);
    o.w = eluf(dd * sum.w + bv.w);
    if (h == 0) ((float4*)xout)[idx] = o;
    if (SCORE) {
        float4 pv = *(const float4*)&p[q << 2];
        float sc = 0.f, nr = 0.f;
        if (h == 0) {
            sc = o.x * pv.x + o.y * pv.y + o.z * pv.z + o.w * pv.w;
            nr = pv.x * pv.x + pv.y * pv.y + pv.z * pv.z + pv.w * pv.w;
        }
#pragma unroll
        for (int m = RL >> 1; m >= 1; m >>= 1) {
            sc += __shfl_xor(sc, m, 64);
            nr += __shfl_xor(nr, m, 64);
        }
        if (rem == 0) score[d] = sc / sqrtf(nr);
    }
}

// ==== fused bitonic top-k: one kernel, internal device barriers ====
// Network identical to verified rounds; invmap written as rank+1 (0 = invalid).
// grid = N/2048 blocks of 1024 (<=4 blocks -> always co-resident, no deadlock).
__device__ __forceinline__ ull cex_shfl(ull v, int st, bool takeMax) {
    ull pv = __shfl_xor(v, st, 64);
    return takeMax ? (v > pv ? v : pv) : (v < pv ? v : pv);
}
__device__ __forceinline__ void cexr(ull& a, ull& b, bool desc) {
    if (desc ? (a < b) : (a > b)) { ull x = a; a = b; b = x; }
}

__global__ void k_topk_f(const float* __restrict__ score, ull* __restrict__ keys,
                         int N, int k, int* __restrict__ out_idx,
                         int* __restrict__ invmap, int* __restrict__ ctr) {
    __shared__ ull sk[4096];
    int tid = threadIdx.x;
    int bid = blockIdx.x;
    int nb = N >> 11;
    // ---- phase 1: full sort of 2048-key window [bid*2048, +2048) ----
    {
        int base = bid << 11;
        int giA = base + tid, giB = giA + 1024;
        ull a = ((ull)f2s(score[giA]) << 32) | (unsigned)(~giA);
        ull b = ((ull)f2s(score[giB]) << 32) | (unsigned)(~giB);
        for (int sz = 2; sz <= 2048; sz <<= 1) {
            int st = sz >> 1;
            if (st >= 64) {
                sk[tid] = a; sk[tid + 1024] = b;
                __syncthreads();
                for (; st >= 64; st >>= 1) {
                    int i = ((tid & ~(st - 1)) << 1) | (tid & (st - 1));
                    int j = i | st;
                    ull u = sk[i], v = sk[j];
                    bool desc = (((base + i) & sz) == 0);
                    if (desc ? (u < v) : (u > v)) { sk[i] = v; sk[j] = u; }
                    __syncthreads();
                }
                a = sk[tid]; b = sk[tid + 1024];
            }
            for (; st >= 1; st >>= 1) {
                bool low = (tid & st) == 0;
                a = cex_shfl(a, st, ((giA & sz) == 0) == low);
                b = cex_shfl(b, st, ((giB & sz) == 0) == low);
            }
        }
        if (nb == 1) {               // N == 2048: done
            if (giA < k) { int j = (int)(~(unsigned)(a & 0xFFFFFFFFu)); out_idx[giA] = j; invmap[j] = giA + 1; }
            if (giB < k) { int j = (int)(~(unsigned)(b & 0xFFFFFFFFu)); out_idx[giB] = j; invmap[j] = giB + 1; }
            return;
        }
        keys[giA] = a; keys[giB] = b;
    }
    // arrive (release: agent-scope fence writes back local L2)
    __syncthreads();
    if (tid == 0) { __threadfence(); atomicAdd(ctr, 1); }

    if (N == 4096) {
        if (bid != 0) return;
        if (tid == 0) { while (atomicAdd(ctr, 0) < 2) ; __threadfence(); }
        __syncthreads();
        // ---- stage sz=4096 final: ranks [0,2048) = k ----
        ull a0 = keys[tid],        a1 = keys[tid + 1024];
        ull a2 = keys[tid + 2048], a3 = keys[tid + 3072];
        cexr(a0, a2, true); cexr(a1, a3, true);      // stride 2048 (keep low half)
        sk[tid] = a0; sk[tid + 1024] = a1;
        __syncthreads();
        for (int st = 1024; st >= 64; st >>= 1) {
            int i = ((tid & ~(st - 1)) << 1) | (tid & (st - 1));
            int j = i | st;
            ull u = sk[i], v = sk[j];
            if (u < v) { sk[i] = v; sk[j] = u; }     // desc
            __syncthreads();
        }
        a0 = sk[tid]; a1 = sk[tid + 1024];
        for (int st = 32; st >= 1; st >>= 1) {
            bool low = (tid & st) == 0;
            a0 = cex_shfl(a0, st, low);
            a1 = cex_shfl(a1, st, low);
        }
        int p, j;
        p = tid;        j = (int)(~(unsigned)(a0 & 0xFFFFFFFFu)); out_idx[p] = j; invmap[j] = p + 1;
        p = tid + 1024; j = (int)(~(unsigned)(a1 & 0xFFFFFFFFu)); out_idx[p] = j; invmap[j] = p + 1;
        return;
    }

    // ---- N == 8192 ----
    if (bid >= 2) return;
    if (tid == 0) { while (atomicAdd(ctr, 0) < 4) ; __threadfence(); }
    __syncthreads();
    {
        // phase 2: stage sz=4096 complete on [bid*4096, +4096)
        int base = bid << 12;
        bool desc = ((base & 4096) == 0);
        ull k0 = keys[base + tid], k1 = keys[base + tid + 1024];
        ull k2 = keys[base + tid + 2048], k3 = keys[base + tid + 3072];
        cexr(k0, k2, desc); cexr(k1, k3, desc);      // stride 2048
        sk[tid] = k0; sk[tid + 1024] = k1; sk[tid + 2048] = k2; sk[tid + 3072] = k3;
        __syncthreads();
        for (int st = 1024; st >= 64; st >>= 1) {
            for (int pp = tid; pp < 2048; pp += 1024) {
                int i = ((pp & ~(st - 1)) << 1) | (pp & (st - 1));
                int j = i | st;
                ull u = sk[i], v = sk[j];
                if (desc ? (u < v) : (u > v)) { sk[i] = v; sk[j] = u; }
            }
            __syncthreads();
        }
        k0 = sk[tid]; k1 = sk[tid + 1024]; k2 = sk[tid + 2048]; k3 = sk[tid + 3072];
        for (int st = 32; st >= 1; st >>= 1) {
            bool low = (tid & st) == 0;
            k0 = cex_shfl(k0, st, desc == low);
            k1 = cex_shfl(k1, st, desc == low);
            k2 = cex_shfl(k2, st, desc == low);
            k3 = cex_shfl(k3, st, desc == low);
        }
        keys[base + tid] = k0; keys[base + tid + 1024] = k1;
        keys[base + tid + 2048] = k2; keys[base + tid + 3072] = k3;
    }
    __syncthreads();
    if (tid == 0) { __threadfence(); atomicAdd(ctr, 1); }
    if (bid != 0) return;
    if (tid == 0) { while (atomicAdd(ctr, 0) < 6) ; __threadfence(); }
    __syncthreads();
    {
        // phase 3: stage sz=8192 (desc everywhere); ranks [0,4096) = k
        ull a0 = keys[tid],        a1 = keys[tid + 1024];
        ull a2 = keys[tid + 2048], a3 = keys[tid + 3072];
        ull b0 = keys[tid + 4096], b1 = keys[tid + 5120];
        ull b2 = keys[tid + 6144], b3 = keys[tid + 7168];
        cexr(a0, b0, true); cexr(a1, b1, true);      // stride 4096 (keep low half)
        cexr(a2, b2, true); cexr(a3, b3, true);
        cexr(a0, a2, true); cexr(a1, a3, true);      // stride 2048 within [0,4096)
        sk[tid] = a0; sk[tid + 1024] = a1; sk[tid + 2048] = a2; sk[tid + 3072] = a3;
        __syncthreads();
        for (int st = 1024; st >= 64; st >>= 1) {
            for (int pp = tid; pp < 2048; pp += 1024) {
                int i = ((pp & ~(st - 1)) << 1) | (pp & (st - 1));
                int j = i | st;
                ull u = sk[i], v = sk[j];
                if (u < v) { sk[i] = v; sk[j] = u; } // desc
            }
            __syncthreads();
        }
        a0 = sk[tid]; a1 = sk[tid + 1024]; a2 = sk[tid + 2048]; a3 = sk[tid + 3072];
        for (int st = 32; st >= 1; st >>= 1) {
            bool low = (tid & st) == 0;
            a0 = cex_shfl(a0, st, low);
            a1 = cex_shfl(a1, st, low);
            a2 = cex_shfl(a2, st, low);
            a3 = cex_shfl(a3, st, low);
        }
        int p, j;
        p = tid;        j = (int)(~(unsigned)(a0 & 0xFFFFFFFFu)); out_idx[p] = j; invmap[j] = p + 1;
        p = tid + 1024; j = (int)(~(unsigned)(a1 & 0xFFFFFFFFu)); out_idx[p] = j; invmap[j] = p + 1;
        p = tid + 2048; j = (int)(~(unsigned)(a2 & 0xFFFFFFFFu)); out_idx[p] = j; invmap[j] = p + 1;
        p = tid + 3072; j = (int)(~(unsigned)(a3 & 0xFFFFFFFFu)); out_idx[p] = j; invmap[j] = p + 1;
    }
}

// ---- fused readout: segment max/sum/count + MLP head + log_softmax, block/graph ----
__global__ void k_finale(const float* __restrict__ x13, const int* __restrict__ gstart,
                         const float* __restrict__ Wl1, const float* __restrict__ Wc,
                         const float* __restrict__ bc, float* __restrict__ out) {
    __shared__ float sm[8][32], ss[8][32];
    __shared__ float h0[64], h1[64], lg[CC];
    int g = blockIdx.x;
    int j0 = gstart[g], j1 = gstart[g + 1];
    int t = threadIdx.x;
    int f = t & 31, r = t >> 5;
    float m = -INFINITY, s = 0.f;
    for (int j = j0 + r; j < j1; j += 8) {
        float v = x13[(j << 5) + f];
        m = fmaxf(m, v);
        s += v;
    }
    sm[r][f] = m; ss[r][f] = s;
    __syncthreads();
    if (t < 32) {
        float mm = sm[0][t], sss = ss[0][t];
        for (int i = 1; i < 8; i++) { mm = fmaxf(mm, sm[i][t]); sss += ss[i][t]; }
        h0[t] = eluf(mm);
        h0[32 + t] = eluf(sss / (float)(j1 - j0));
    }
    __syncthreads();
    if (t < 64) {
        float sum = 0.f;
        for (int kk = 0; kk < 64; kk++) sum += h0[kk] * Wl1[kk * 64 + t];
        h1[t] = eluf(sum);
    }
    __syncthreads();
    if (t < CC) {
        float sum = bc[t];
        for (int kk = 0; kk < 64; kk++) sum += h1[kk] * Wc[kk * CC + t];
        lg[t] = sum;
    }
    __syncthreads();
    if (t == 0) {
        float mm = -1e30f;
        for (int c = 0; c < CC; c++) mm = fmaxf(mm, lg[c]);
        float se = 0.f;
        for (int c = 0; c < CC; c++) se += expf(lg[c] - mm);
        float lse = mm + logf(se);
        for (int c = 0; c < CC; c++) out[g * CC + c] = lg[c] - lse;
    }
}

extern "C" void kernel_launch(void* const* d_in, const int* in_sizes, int n_in,
                              void* d_out, int out_size, void* d_ws, size_t ws_size,
                              hipStream_t stream) {
    const float* x = (const float*)d_in[0];
    const int* ei = (const int*)d_in[1];
    const int* batch = (const int*)d_in[2];
    const float* W1 = (const float*)d_in[3];  const float* b1 = (const float*)d_in[4];
    const float* W2 = (const float*)d_in[5];  const float* b2 = (const float*)d_in[6];
    const float* W3 = (const float*)d_in[7];  const float* b3 = (const float*)d_in[8];
    const float* W4 = (const float*)d_in[9];  const float* b4 = (const float*)d_in[10];
    const float* W5 = (const float*)d_in[11]; const float* b5 = (const float*)d_in[12];
    const float* W6 = (const float*)d_in[13]; const float* b6 = (const float*)d_in[14];
    const float* W7 = (const float*)d_in[15]; const float* b7 = (const float*)d_in[16];
    const float* p1 = (const float*)d_in[17];
    const float* p2 = (const float*)d_in[18];
    const float* p3 = (const float*)d_in[19];
    const float* Wl1 = (const float*)d_in[20];
    const float* Wc = (const float*)d_in[21];
    const float* bc = (const float*)d_in[22];
    float* out = (float*)d_out;
    (void)in_sizes; (void)n_in; (void)out_size; (void)ws_size;

    char* w = (char*)d_ws;
    size_t off = 0;
    auto alloc = [&](size_t bytes) -> char* {
        char* p = w + off;
        off = (off + bytes + 255) & ~(size_t)255;
        return p;
    };

    // ---- zero-initialized span (single small memset) ----
    size_t zero_begin = off;
    int* cnt1 = (int*)alloc(NN * 4);
    int* pos2 = (int*)alloc(NN * 4);     // orig -> level2 rank+1 (0 = invalid)
    int* inv4 = (int*)alloc(KK1 * 4);    // level2 -> level3 rank+1
    int* inv6 = (int*)alloc(KK2 * 4);    // level3 -> level4 rank+1
    int* tkctr = (int*)alloc(2 * 4);     // topk barrier counters (pool1, pool2)
    size_t zero_len = off - zero_begin;

    // ---- uninitialized scratch ----
    float* dinv2 = (float*)alloc(KK1 * 4);
    float* dinv3 = (float*)alloc(KK2 * 4);
    float* dinv4 = (float*)alloc(KK3 * 4);
    int* roff2 = (int*)alloc(KK1 * 4); int* deg2 = (int*)alloc(KK1 * 4);
    int* roff3 = (int*)alloc(KK2 * 4); int* deg3 = (int*)alloc(KK2 * 4);
    int* roff4 = (int*)alloc(KK3 * 4); int* deg4 = (int*)alloc(KK3 * 4);
    int* csr1 = (int*)alloc((size_t)NN * PITCH * 4);   // 4 MB ELL each
    int* csr2 = (int*)alloc((size_t)NN * PITCH * 4);
    int* csr3 = (int*)alloc((size_t)NN * PITCH * 4);
    int* csr4 = (int*)alloc((size_t)NN * PITCH * 4);
    float* xW = (float*)alloc((size_t)262144 * 4);
    float* x1 = (float*)alloc((size_t)NN * 32 * 4);
    float* x3 = (float*)alloc((size_t)KK1 * 64 * 4);
    float* x5 = (float*)alloc((size_t)KK2 * 128 * 4);
    float* x7 = (float*)alloc((size_t)KK3 * 256 * 4);
    float* x9 = (float*)alloc((size_t)KK2 * 128 * 4);
    float* x11 = (float*)alloc((size_t)KK1 * 64 * 4);
    float* x13 = (float*)alloc((size_t)NN * 32 * 4);
    float* score1 = (float*)alloc(NN * 4);
    float* score2 = (float*)alloc(KK1 * 4);
    float* score3 = (float*)alloc(KK2 * 4);
    int* i2 = (int*)alloc(KK1 * 4);
    int* i4 = (int*)alloc(KK2 * 4);
    int* i6 = (int*)alloc(KK3 * 4);
    ull* keys = (ull*)alloc((size_t)NN * 8);
    int* gstart = (int*)alloc((GG + 1) * 4);

    hipMemsetAsync(w + zero_begin, 0, zero_len, stream);

    const int B = 256;
    // ---- fused: level-1 edge pass (ELL scatter + gbounds) || gemm1 ----
    k_init<<<1280, B, 0, stream>>>(ei, cnt1, csr1, batch, gstart, x, W1, xW);

    // ---- gcn1 propagate (+score1), split S=8 ----
    k_prop<5, 1, 1, 3><<<2048, B, 0, stream>>>(csr1, nullptr, cnt1, nullptr, xW, b1,
                                               x1, p1, score1);

    // ---- pool1: top-4096 of 8192 (single fused kernel); pool+gemm2+subset ----
    k_topk_f<<<4, 1024, 0, stream>>>(score1, keys, NN, KK1, i2, pos2, tkctr);
    k_pool_gemm_sub<KK1, 32, 64, 1><<<256 + KK1 / 4, B, 0, stream>>>(
        x1, score1, i2, xW, W2, csr1, nullptr, cnt1, pos2, csr2, roff2, deg2, dinv2);

    // ---- gcn2 propagate (+score2), split S=4 ----
    k_prop<6, 1, 0, 2><<<1024, B, 0, stream>>>(csr2, roff2, deg2, dinv2, xW, b2,
                                               x3, p2, score2);

    // ---- pool2: top-2048 of 4096; pool+gemm3+subset ----
    k_topk_f<<<2, 1024, 0, stream>>>(score2, keys, KK1, KK2, i4, inv4, tkctr + 1);
    k_pool_gemm_sub<KK2, 64, 128, 0><<<256 + KK2 / 4, B, 0, stream>>>(
        x3, score2, i4, xW, W3, csr2, roff2, deg2, inv4, csr3, roff3, deg3, dinv3);

    // ---- gcn3 propagate (+score3), split S=2 ----
    k_prop<7, 1, 0, 1><<<512, B, 0, stream>>>(csr3, roff3, deg3, dinv3, xW, b3,
                                              x5, p3, score3);

    // ---- pool3: top-1024 of 2048; pool+gemm4+subset ----
    k_topk_f<<<1, 1024, 0, stream>>>(score3, keys, KK2, KK3, i6, inv6, nullptr);
    k_pool_gemm_sub<KK3, 128, 256, 0><<<256 + KK3 / 4, B, 0, stream>>>(
        x5, score3, i6, xW, W4, csr3, roff3, deg3, inv6, csr4, roff4, deg4, dinv4);

    // ---- gcn4 propagate, split S=2 ----
    k_prop<8, 0, 0, 1><<<512, B, 0, stream>>>(csr4, roff4, deg4, dinv4, xW, b4,
                                              x7, nullptr, nullptr);

    // ---- gcn5 (unpool3 fused into X staging), split S=4 ----
    k_gemm_up<<<dim3(KK2 / 32, 4), B, 0, stream>>>(x7, inv6, x5, 256, 128,
                                                   W5, xW, KK2, 384, 128);
    k_prop<7, 0, 0, 2><<<1024, B, 0, stream>>>(csr3, roff3, deg3, dinv3, xW, b5,
                                               x9, nullptr, nullptr);

    // ---- gcn6 (unpool2 fused), split S=4 ----
    k_gemm_up<<<dim3(KK1 / 32, 2), B, 0, stream>>>(x9, inv4, x3, 128, 64,
                                                   W6, xW, KK1, 192, 64);
    k_prop<6, 0, 0, 2><<<1024, B, 0, stream>>>(csr2, roff2, deg2, dinv2, xW, b6,
                                               x11, nullptr, nullptr);

    // ---- gcn7 (unpool1 fused; original weighted adjacency), split S=8 ----
    k_gemm_up<<<dim3(NN / 32, 1), B, 0, stream>>>(x11, pos2, x1, 64, 32,
                                                  W7, xW, NN, 96, 32);
    k_prop<5, 0, 1, 3><<<2048, B, 0, stream>>>(csr1, nullptr, cnt1, nullptr, xW, b7,
                                               x13, nullptr, nullptr);

    // ---- fused readout ----
    k_finale<<<GG, B, 0, stream>>>(x13, gstart, Wl1, Wc, bc, out);
}